// Round 7
// baseline (272.936 us; speedup 1.0000x reference)
//
#include <hip/hip_runtime.h>
#include <hip/hip_bf16.h>
#include <stdint.h>

#define M_ROWS 4096
#define N_REFS 32768
#define DIM    512
#define BM     128
#define BN     128
#define BK     64
#define NKT    (DIM / BK)          // 8 K-tiles
#define BUFA   16384               // A: 128 rows x 128B
#define BUFSZ  32768               // A 16KB + B 16KB per buffer
#define NTILE  (N_REFS / BN)       // 256
#define MTILE  (M_ROWS / BM)       // 32

typedef __attribute__((ext_vector_type(8))) short short8;
typedef __attribute__((ext_vector_type(4))) float f32x4;

__device__ __forceinline__ uint32_t f2bf1(float f) {
  uint32_t u = __float_as_uint(f);
  return (u + 0x7FFFu + ((u >> 16) & 1u)) >> 16;   // RNE fp32 -> bf16
}

__global__ void prep_rows(const float* __restrict__ src, uint16_t* __restrict__ dst,
                          float* __restrict__ sq) {
  int row = blockIdx.x;
  int t = threadIdx.x;                       // 256 threads, 2 elems each
  const float2* s = (const float2*)(src + (size_t)row * DIM);
  float2 v = s[t];
  uint32_t packed = f2bf1(v.x) | (f2bf1(v.y) << 16);
  ((uint32_t*)(dst + (size_t)row * DIM))[t] = packed;
  float ss = v.x * v.x + v.y * v.y;
  #pragma unroll
  for (int d = 32; d >= 1; d >>= 1) ss += __shfl_down(ss, d, 64);
  __shared__ float wsum[4];
  int w = t >> 6, lane = t & 63;
  if (lane == 0) wsum[w] = ss;
  __syncthreads();
  if (t == 0) sq[row] = wsum[0] + wsum[1] + wsum[2] + wsum[3];
}

// 128x128 tile, 8 waves of 64x32 (2 wr x 4 wc), acc[4][2] = 32 regs/lane ->
// ~120 unified regs/wave -> 2 blocks/CU x 8 waves = 16 waves/CU target (the
// occupancy that R1/R3/R6 never reached with 64-reg accumulators). Simple
// double-buffered loop: stage(t+1) -> read+MFMA(t) -> syncthreads (compiler
// drains vmcnt; TLP at 4 waves/SIMD hides the latency instead of a static
// schedule). BK=64 / 128B LDS rows / verified zero-conflict XOR swizzle.
__global__ __launch_bounds__(512, 2) void ask_main(
    const uint16_t* __restrict__ xbf, const uint16_t* __restrict__ rbf,
    const float* __restrict__ x2, const float* __restrict__ r2,
    const int* __restrict__ y, const int* __restrict__ yref,
    float* __restrict__ totG, float* __restrict__ matchG)
{
  __shared__ unsigned char smem[2 * BUFSZ];   // 64 KB

  const int tid  = threadIdx.x;
  const int w    = tid >> 6, lane = tid & 63;
  const int wr   = w >> 2,  wc   = w & 3;      // 2 x 4 wave grid (64x32 each)
  const int l15  = lane & 15, l4 = lane >> 4;

  // XCD-aware swizzle: nwg = 8192 % 8 == 0 -> simple form bijective.
  // ntile varies fastest within an XCD chunk -> A-panel L2-resident per XCD.
  const int wg    = blockIdx.x;
  const int swz   = (wg & 7) * 1024 + (wg >> 3);
  const int mtile = swz >> 8, ntile = swz & 255;
  const int bm = mtile * BM, bn = ntile * BN;

  // ---- staging: thread tid covers (row = tid>>3 within 64-row chunk, slot = tid&7)
  // LDS write linear (chunk*8192 + tid*16); read XORs slot with (row&7), so the
  // global source column-group is pre-permuted by the same involution (rule #21).
  const int strow = tid >> 3;                         // 0..63
  const int sgsw  = ((tid & 7) ^ (strow & 7)) * 8;    // pre-swizzled col (elems)
  const uint16_t* aBase = xbf + (size_t)(bm + strow) * DIM + sgsw;
  const uint16_t* bBase = rbf + (size_t)(bn + strow) * DIM + sgsw;

#define GLL(srcp, dstoff)                                                        \
  __builtin_amdgcn_global_load_lds(                                              \
      (const __attribute__((address_space(1))) void*)(srcp),                     \
      (__attribute__((address_space(3))) void*)(smem + (dstoff)), 16, 0, 0)

  // stage K-tile kt into buffer b: A rows 0-63, 64-127; B rows 0-63, 64-127
#define STAGE(kt, b)                                                             \
  GLL(aBase + (kt) * BK,            (b) * BUFSZ + 0 * 8192 + tid * 16);          \
  GLL(aBase + (kt) * BK + 64 * DIM, (b) * BUFSZ + 1 * 8192 + tid * 16);          \
  GLL(bBase + (kt) * BK,            (b) * BUFSZ + BUFA + 0 * 8192 + tid * 16);   \
  GLL(bBase + (kt) * BK + 64 * DIM, (b) * BUFSZ + BUFA + 1 * 8192 + tid * 16)

  // ---- fragment read lane-bases ----
  // row&7 == l15&7 for all frag rows (offsets are multiples of 8 rows), so
  // slot(ks) = (ks*4 + l4) ^ (l15&7); addr = row*128 + slot*16.
  const int slot0 = ((l4)     ^ (l15 & 7)) * 16;
  const int slot1 = ((4 | l4) ^ (l15 & 7)) * 16;
  const int aRow  = (wr * 64 + l15) * 128;            // + mf*2048
  const int bRow  = BUFA + (wc * 32 + l15) * 128;     // + nf*2048

  f32x4 acc[4][2];
  const f32x4 fz = {0.f, 0.f, 0.f, 0.f};
  #pragma unroll
  for (int mf = 0; mf < 4; ++mf)
    #pragma unroll
    for (int nf = 0; nf < 2; ++nf) acc[mf][nf] = fz;

  // ---- prologue: stage tile 0 ----
  STAGE(0, 0);
  __syncthreads();

  #pragma unroll
  for (int t = 0; t < NKT; ++t) {
    const int buf = t & 1;
    if (t + 1 < NKT) { STAGE(t + 1, buf ^ 1); }

    const unsigned char* pA = smem + buf * BUFSZ + aRow;
    const unsigned char* pB = smem + buf * BUFSZ + bRow;

    #pragma unroll
    for (int ks = 0; ks < 2; ++ks) {
      const int sl = ks ? slot1 : slot0;
      short8 afr[4], bfr[2];
      #pragma unroll
      for (int nf = 0; nf < 2; ++nf) bfr[nf] = *(const short8*)(pB + nf * 2048 + sl);
      #pragma unroll
      for (int mf = 0; mf < 4; ++mf) afr[mf] = *(const short8*)(pA + mf * 2048 + sl);
      #pragma unroll
      for (int mf = 0; mf < 4; ++mf)
        #pragma unroll
        for (int nf = 0; nf < 2; ++nf)
          acc[mf][nf] = __builtin_amdgcn_mfma_f32_16x16x32_bf16(afr[mf], bfr[nf], acc[mf][nf], 0, 0, 0);
    }
    __syncthreads();   // drains vmcnt (next tile resident) + orders buffer reuse
  }

  // ---- fused epilogue: e = exp(-sqrt(x2 + r2 - 2*dot)), per-row total/match ----
  float* redf = (float*)smem;            // [2 arr][128 rowlocal][4 wc] = 4 KB
  #pragma unroll
  for (int mf = 0; mf < 4; ++mf) {
    const int growb = bm + wr * 64 + mf * 16 + l4 * 4;
    float x2r[4]; int yy[4];
    #pragma unroll
    for (int g = 0; g < 4; ++g) { x2r[g] = x2[growb + g]; yy[g] = y[growb + g]; }
    float tt[4] = {0.f, 0.f, 0.f, 0.f}, mm[4] = {0.f, 0.f, 0.f, 0.f};
    #pragma unroll
    for (int nf = 0; nf < 2; ++nf) {
      const int gcol = bn + wc * 32 + nf * 16 + l15;
      const float r2c = r2[gcol];
      const int   cls = yref[gcol];
      #pragma unroll
      for (int g = 0; g < 4; ++g) {
        float t2 = fmaf(-2.0f, acc[mf][nf][g], x2r[g] + r2c);
        t2 = fmaxf(t2, 0.0f);
        float d = __builtin_amdgcn_sqrtf(t2);
        float e = __builtin_amdgcn_exp2f(-1.44269504088896f * d);
        tt[g] += e;
        mm[g] += (cls == yy[g]) ? e : 0.0f;
      }
    }
    #pragma unroll
    for (int g = 0; g < 4; ++g) {
      float a = tt[g], b = mm[g];
      #pragma unroll
      for (int d = 1; d <= 8; d <<= 1) {
        a += __shfl_xor(a, d, 64);
        b += __shfl_xor(b, d, 64);
      }
      if (l15 == 0) {   // lanes 0,16,32,48 -> l4 = 0..3 -> 16 rows per wave-mf
        const int rl = wr * 64 + mf * 16 + l4 * 4 + g;
        redf[(0 * 128 + rl) * 4 + wc] = a;
        redf[(1 * 128 + rl) * 4 + wc] = b;
      }
    }
  }
  __syncthreads();
  if (tid < 256) {
    const int arr = tid >> 7, rl = tid & 127;       // 2 arrays x 128 rows
    const float* p = redf + (arr * 128 + rl) * 4;
    const float s = p[0] + p[1] + p[2] + p[3];
    atomicAdd((arr ? matchG : totG) + bm + rl, s);
  }
#undef GLL
#undef STAGE
}

__global__ void finalize_loss(const float* __restrict__ totG, const float* __restrict__ matchG,
                              float* __restrict__ out) {
  __shared__ float red[256];
  int t = threadIdx.x;
  float s = 0.f;
  for (int r = t; r < M_ROWS; r += 256)
    s += logf(matchG[r] / totG[r] + 1e-6f);
  red[t] = s;
  __syncthreads();
  for (int off = 128; off >= 1; off >>= 1) {
    if (t < off) red[t] += red[t + off];
    __syncthreads();
  }
  if (t == 0) out[0] = -red[0] / (float)M_ROWS;
}

extern "C" void kernel_launch(void* const* d_in, const int* in_sizes, int n_in,
                              void* d_out, int out_size, void* d_ws, size_t ws_size,
                              hipStream_t stream) {
  const float* x    = (const float*)d_in[0];
  const float* xref = (const float*)d_in[1];
  const int*   y    = (const int*)d_in[2];
  const int*   yref = (const int*)d_in[3];
  float* out = (float*)d_out;

  uint8_t* ws = (uint8_t*)d_ws;
  uint16_t* xbf   = (uint16_t*)(ws);                    //  4 MB
  uint16_t* rbf   = (uint16_t*)(ws + 4194304);          // 32 MB
  float*    x2    = (float*)(ws + 37748736);            // 16 KB
  float*    r2    = (float*)(ws + 37765120);            // 128 KB
  float*    totG  = (float*)(ws + 37896192);            // 16 KB
  float*    matchG= (float*)(ws + 37912576);            // 16 KB

  hipMemsetAsync(totG, 0, 2 * M_ROWS * sizeof(float), stream);

  prep_rows<<<M_ROWS, 256, 0, stream>>>(x, xbf, x2);
  prep_rows<<<N_REFS, 256, 0, stream>>>(xref, rbf, r2);
  ask_main<<<MTILE * NTILE, 512, 0, stream>>>(xbf, rbf, x2, r2, y, yref, totG, matchG);
  finalize_loss<<<1, 256, 0, stream>>>(totG, matchG, out);
}